// Round 8
// baseline (1330.119 us; speedup 1.0000x reference)
//
#include <hip/hip_runtime.h>
#include <math.h>

#define BATCH 256
#define SEQ   2048
#define HID   128
#define VOCAB 50000
#define RPB   16                 // batch rows per block
#define NRB   (BATCH / RPB)      // 16 blocks

typedef _Float16 v2h __attribute__((ext_vector_type(2)));
typedef _Float16 v4h __attribute__((ext_vector_type(4)));
typedef _Float16 v8h __attribute__((ext_vector_type(8)));
typedef float    v4f __attribute__((ext_vector_type(4)));

template<int CTRL>
__device__ __forceinline__ float dpp_movf(float x) {
    return __builtin_bit_cast(float,
        __builtin_amdgcn_update_dpp(0, __builtin_bit_cast(int, x),
                                    CTRL, 0xF, 0xF, false));
}
__device__ __forceinline__ float quad_reduce(float x) {
    x += dpp_movf<0xB1>(x);
    x += dpp_movf<0x4E>(x);
    return x;
}
__device__ __forceinline__ float fast_rcp(float x) { return __builtin_amdgcn_rcpf(x); }
__device__ __forceinline__ float dot2(v2h a, v2h b, float c) {
    return __builtin_amdgcn_fdot2(a, b, c, false);
}
// tanh(z) = 1 - 2/(exp2(z*2log2e)+1)
__device__ __forceinline__ float fast_tanhf(float z) {
    return 1.0f - 2.0f * fast_rcp(__builtin_amdgcn_exp2f(z * 2.885390081777927f) + 1.0f);
}
#define BCH(u) __builtin_bit_cast(v2h, (u))

// ---------------- Y = emb @ W_ih[0] + b[0]  (f16 out) ----------------
__global__ __launch_bounds__(512, 2) void emb_proj_kernel(
    const float* __restrict__ emb,   // [VOCAB, 128]
    const float* __restrict__ W_ih,  // [2, 128, 128] (layer 0 used)
    const float* __restrict__ bias,  // [2, 128]
    _Float16*    __restrict__ Y)     // [VOCAB, 128]
{
    const int tid  = threadIdx.x;
    const int wave = tid >> 6;
    const int lane = tid & 63;
    const int j    = wave * 16 + (lane >> 2);
    const int q    = lane & 3;

    __shared__ __align__(16) _Float16 xr[HID];

    v2h w[16];
#pragma unroll
    for (int i = 0; i < 16; ++i) {
        const int k = q * 32 + 2 * i;
        w[i] = v2h{(_Float16)W_ih[k * HID + j], (_Float16)W_ih[(k + 1) * HID + j]};
    }
    const float bj = bias[j];
    const float4* embf4 = (const float4*)emb;

    for (int r = blockIdx.x; r < VOCAB; r += gridDim.x) {
        if (tid < 32) {
            float4 v = embf4[(size_t)r * 32 + tid];
            uint a01 = __builtin_bit_cast(uint, __builtin_amdgcn_cvt_pkrtz(v.x, v.y));
            uint a23 = __builtin_bit_cast(uint, __builtin_amdgcn_cvt_pkrtz(v.z, v.w));
            ((uint2*)&xr[0])[tid] = uint2{a01, a23};
        }
        __syncthreads();
        const uint4* xp = (const uint4*)&xr[0] + q * 4;
        float acc = 0.f;
#pragma unroll
        for (int i = 0; i < 4; ++i) {
            const uint4 xu = xp[i];
            acc = dot2(BCH(xu.x), w[4*i+0], acc);
            acc = dot2(BCH(xu.y), w[4*i+1], acc);
            acc = dot2(BCH(xu.z), w[4*i+2], acc);
            acc = dot2(BCH(xu.w), w[4*i+3], acc);
        }
        acc = quad_reduce(acc) + bj;
        if (q == 0) Y[(size_t)r * HID + j] = (_Float16)acc;
        __syncthreads();
    }
}

// ---------------- batched recurrent kernel: 16 rows/block, real MFMA ----------------
// Block = 16 batch rows; 8 waves; wave w owns output cols [16w, 16w+16) of
// both layers. Per step t (h1 lagged 1 step):
//   h0(t)   = tanh(Whh0 h0(t-1) + Y[tok_r(t)])        rows alive: t < len_r
//   h1(t-1) = tanh(Wih1 h0(t-1) + Whh1 h1(t-2) + b1)  rows alive: 1<=t<=len_r
// A-fragments (h state, 16 real rows) from swizzled LDS; B-fragments
// (weights) static in VGPRs. D rows map back via per-lane register copies
// (hp0/hp1) for masking. One barrier per step.
// LDS layout: row-major [16][128] f16, 16B chunks XOR-swizzled by row:
//   phys_chunk = (logical_chunk ^ row) & 15 (involution, read==write).
__global__ __launch_bounds__(512, 1) void rnn_batch16_kernel(
    const int*      __restrict__ x,        // [B, T]
    const int*      __restrict__ lengths,  // [B]
    const _Float16* __restrict__ Y,        // [VOCAB, 128]
    const float*    __restrict__ W_ih,     // [2, 128, 128] (layer 1 used)
    const float*    __restrict__ W_hh,     // [2, 128, 128]
    const float*    __restrict__ bias,     // [2, 128] (layer 1 used)
    const float*    __restrict__ cls_w,    // [128]
    const float*    __restrict__ cls_b,    // [1]
    float*          __restrict__ out)      // [B]
{
    const int blk  = blockIdx.x;
    const int tid  = threadIdx.x;
    const int w    = tid >> 6;
    const int lane = tid & 63;
    const int rg   = lane >> 4;      // A: k-group | D: row-group
    const int ln   = lane & 15;      // A: row m   | B/D: col n
    const int col  = w * 16 + ln;

    __shared__ __align__(16) _Float16 h0s[2][RPB * HID];
    __shared__ __align__(16) _Float16 h1s[2][RPB * HID];
    __shared__ __align__(16) float    clsb[RPB][HID];

    for (int i = tid; i < 2 * RPB * HID; i += 512) {
        ((_Float16*)h0s)[i] = (_Float16)0.f;
        ((_Float16*)h1s)[i] = (_Float16)0.f;
    }

    const int rb = blk * RPB;
    int len4[4];
#pragma unroll
    for (int r = 0; r < 4; ++r) len4[r] = lengths[rb + 4 * rg + r];
    int Tmax = 0;
    for (int i = 0; i < RPB; ++i) Tmax = max(Tmax, lengths[rb + i]);

    // B-fragments: lane 16*kg+n holds B[k=32kt+8kg+e][n] (R4-verified layout)
    v8h Bhh0[4], Bih1[4], Bhh1[4];
#pragma unroll
    for (int kt = 0; kt < 4; ++kt) {
#pragma unroll
        for (int e = 0; e < 8; ++e) {
            const int k = kt * 32 + rg * 8 + e;
            Bhh0[kt][e] = (_Float16)W_hh[k * HID + col];
            Bih1[kt][e] = (_Float16)W_ih[HID * HID + k * HID + col];
            Bhh1[kt][e] = (_Float16)W_hh[HID * HID + k * HID + col];
        }
    }
    const float b1c = bias[HID + col];

    // Y/token rings (this lane's 4 D-rows at its col), depth 2
    const int r0 = rb + 4 * rg;
    _Float16 yA[4], yB[4]; int tA[4], tB[4];
#pragma unroll
    for (int r = 0; r < 4; ++r) {
        yA[r] = Y[(size_t)x[(r0 + r) * SEQ + 0] * HID + col];
        yB[r] = Y[(size_t)x[(r0 + r) * SEQ + 1] * HID + col];
        tA[r] = x[(r0 + r) * SEQ + 2];
        tB[r] = x[(r0 + r) * SEQ + 3];
    }

    v4h hp0 = {0,0,0,0}, hp1 = {0,0,0,0};   // register D-layout h copies

    __syncthreads();

#define PHASE(RD, WR, YR, TR, TT)                                            \
    {                                                                        \
        v8h A0[4], A1[4];                                                    \
        const char* ab0 = (const char*)&h0s[RD][0] + ln * 256;               \
        const char* ab1 = (const char*)&h1s[RD][0] + ln * 256;               \
        _Pragma("unroll")                                                    \
        for (int kt = 0; kt < 4; ++kt) {                                     \
            const int aoff = (((kt * 4 + rg) ^ ln) & 15) * 16;               \
            A0[kt] = *(const v8h*)(ab0 + aoff);                              \
            A1[kt] = *(const v8h*)(ab1 + aoff);                              \
        }                                                                    \
        v4f c0 = {0,0,0,0}, c1 = {0,0,0,0};                                  \
        _Pragma("unroll")                                                    \
        for (int kt = 0; kt < 4; ++kt)                                       \
            c0 = __builtin_amdgcn_mfma_f32_16x16x32_f16(A0[kt], Bhh0[kt], c0, 0, 0, 0); \
        _Pragma("unroll")                                                    \
        for (int kt = 0; kt < 4; ++kt)                                       \
            c1 = __builtin_amdgcn_mfma_f32_16x16x32_f16(A0[kt], Bih1[kt], c1, 0, 0, 0); \
        _Pragma("unroll")                                                    \
        for (int kt = 0; kt < 4; ++kt)                                       \
            c1 = __builtin_amdgcn_mfma_f32_16x16x32_f16(A1[kt], Bhh1[kt], c1, 0, 0, 0); \
        float yf[4];                                                         \
        _Pragma("unroll")                                                    \
        for (int r = 0; r < 4; ++r) yf[r] = (float)YR[r];                    \
        _Pragma("unroll")                                                    \
        for (int r = 0; r < 4; ++r) {                                        \
            const int tok = TR[r];                                           \
            YR[r] = Y[(size_t)tok * HID + col];                              \
            const int tnx = (TT + 4 < SEQ) ? (TT + 4) : (SEQ - 1);           \
            TR[r] = x[(r0 + r) * SEQ + tnx];                                 \
        }                                                                    \
        _Pragma("unroll")                                                    \
        for (int r = 0; r < 4; ++r) {                                        \
            const int row = 4 * rg + r;                                      \
            const _Float16 t0 = (_Float16)fast_tanhf(c0[r] + yf[r]);         \
            const _Float16 t1 = (_Float16)fast_tanhf(c1[r] + b1c);           \
            const _Float16 n0 = (TT < len4[r]) ? t0 : hp0[r];                \
            const _Float16 n1 = (TT >= 1 && TT <= len4[r]) ? t1 : hp1[r];    \
            hp0[r] = n0; hp1[r] = n1;                                        \
            const int cl   = ((2 * w + (ln >> 3)) ^ row) & 15;               \
            const int woff = row * 256 + cl * 16 + (ln & 7) * 2;             \
            *(_Float16*)((char*)&h0s[WR][0] + woff) = n0;                    \
            *(_Float16*)((char*)&h1s[WR][0] + woff) = n1;                    \
        }                                                                    \
        __syncthreads();                                                     \
    }

    for (int t = 0; t <= Tmax; t += 2) {
        PHASE(0, 1, yA, tA, t)
        if (t + 1 <= Tmax) PHASE(1, 0, yB, tB, t + 1)
    }
#undef PHASE

    // classifier: out[row] = sigmoid(h1_final . cls_w + cls_b)
#pragma unroll
    for (int r = 0; r < 4; ++r) clsb[4 * rg + r][col] = (float)hp1[r];
    __syncthreads();
    {
        const int row = tid >> 5, s = tid & 31;
        const float4 hv = *(const float4*)&clsb[row][4 * s];
        const float4 wv = *(const float4*)&cls_w[4 * s];
        float d = hv.x * wv.x + hv.y * wv.y + hv.z * wv.z + hv.w * wv.w;
#pragma unroll
        for (int o = 16; o >= 1; o >>= 1) d += __shfl_xor(d, o, 32);
        if (s == 0) {
            const float z = d + cls_b[0];
            out[rb + row] = fast_rcp(1.0f + __builtin_amdgcn_exp2f(-z * 1.4426950408889634f));
        }
    }
}

extern "C" void kernel_launch(void* const* d_in, const int* in_sizes, int n_in,
                              void* d_out, int out_size, void* d_ws, size_t ws_size,
                              hipStream_t stream) {
    const int*   x       = (const int*)  d_in[0];
    const int*   lengths = (const int*)  d_in[1];
    const float* emb     = (const float*)d_in[2];
    const float* W_ih    = (const float*)d_in[3];
    const float* W_hh    = (const float*)d_in[4];
    const float* bias    = (const float*)d_in[5];
    const float* cls_w   = (const float*)d_in[6];
    const float* cls_b   = (const float*)d_in[7];
    float*       out     = (float*)      d_out;

    _Float16* Yws = (_Float16*)d_ws;     // 50000*128*2 B = 12.8 MB

    emb_proj_kernel<<<2048, 512, 0, stream>>>(emb, W_ih, bias, Yws);
    rnn_batch16_kernel<<<NRB, 512, 0, stream>>>(
        x, lengths, Yws, W_ih, W_hh, bias, cls_w, cls_b, out);
}

// Round 9
// 834.680 us; speedup vs baseline: 1.5936x; 1.5936x over previous
//
#include <hip/hip_runtime.h>
#include <math.h>

#define BATCH 256
#define SEQ   2048
#define HID   128
#define NTHR  256
#define VOCAB 50000

typedef _Float16 v2h __attribute__((ext_vector_type(2)));

template<int CTRL>
__device__ __forceinline__ float dpp_movf(float x) {
    return __builtin_bit_cast(float,
        __builtin_amdgcn_update_dpp(0, __builtin_bit_cast(int, x),
                                    CTRL, 0xF, 0xF, false));
}
__device__ __forceinline__ float quad_reduce(float x) {
    x += dpp_movf<0xB1>(x);   // + lane^1
    x += dpp_movf<0x4E>(x);   // + lane^2
    return x;                 // full quad sum in all 4 lanes
}
__device__ __forceinline__ float fast_rcp(float x) { return __builtin_amdgcn_rcpf(x); }
__device__ __forceinline__ float dot2(v2h a, v2h b, float c) {
    return __builtin_amdgcn_fdot2(a, b, c, false);   // v_dot2_f32_f16
}
#define BCH(u) __builtin_bit_cast(v2h, (u))

// Barrier WITHOUT vmcnt drain: makes LDS writes visible (lgkmcnt only) and
// leaves register-destined global loads in flight across the barrier.
// (__syncthreads would emit s_waitcnt vmcnt(0) and serialize the Y-ring
// prefetch latency into every phase.)
__device__ __forceinline__ void barrier_lds() {
    asm volatile("s_waitcnt lgkmcnt(0)\n\ts_barrier" ::: "memory");
}

// ---------------- Y = emb @ W_ih[0] + b[0]  (f16 out) ----------------
__global__ __launch_bounds__(512, 2) void emb_proj_kernel(
    const float* __restrict__ emb,   // [VOCAB, 128]
    const float* __restrict__ W_ih,  // [2, 128, 128] (layer 0 used)
    const float* __restrict__ bias,  // [2, 128]
    _Float16*    __restrict__ Y)     // [VOCAB, 128]
{
    const int tid  = threadIdx.x;
    const int wave = tid >> 6;
    const int lane = tid & 63;
    const int j    = wave * 16 + (lane >> 2);
    const int q    = lane & 3;

    __shared__ __align__(16) _Float16 xr[HID];

    v2h w[16];
#pragma unroll
    for (int i = 0; i < 16; ++i) {
        const int k = q * 32 + 2 * i;
        w[i] = v2h{(_Float16)W_ih[k * HID + j], (_Float16)W_ih[(k + 1) * HID + j]};
    }
    const float bj = bias[j];
    const float4* embf4 = (const float4*)emb;

    for (int r = blockIdx.x; r < VOCAB; r += gridDim.x) {
        if (tid < 32) {
            float4 v = embf4[(size_t)r * 32 + tid];
            uint a01 = __builtin_bit_cast(uint, __builtin_amdgcn_cvt_pkrtz(v.x, v.y));
            uint a23 = __builtin_bit_cast(uint, __builtin_amdgcn_cvt_pkrtz(v.z, v.w));
            ((uint2*)&xr[0])[tid] = uint2{a01, a23};
        }
        __syncthreads();
        const uint4* xp = (const uint4*)&xr[0] + q * 4;
        float acc = 0.f;
#pragma unroll
        for (int i = 0; i < 4; ++i) {
            const uint4 xu = xp[i];
            acc = dot2(BCH(xu.x), w[4*i+0], acc);
            acc = dot2(BCH(xu.y), w[4*i+1], acc);
            acc = dot2(BCH(xu.z), w[4*i+2], acc);
            acc = dot2(BCH(xu.w), w[4*i+3], acc);
        }
        acc = quad_reduce(acc) + bj;
        if (q == 0) Y[(size_t)r * HID + j] = (_Float16)acc;
        __syncthreads();
    }
}

// ---------------- recurrent kernel: dot2 VALU, J=2 cols/thread ----------------
// Identical to R7 except the in-loop barrier is lgkmcnt-only (barrier_lds),
// so the Y-gather ring's global loads stay in flight across phases.
__global__ __launch_bounds__(NTHR, 1) void rnn_dot2_kernel(
    const int*      __restrict__ x,        // [B, T]
    const int*      __restrict__ lengths,  // [B]
    const _Float16* __restrict__ Y,        // [VOCAB, 128] = emb@Wih0 + b0
    const float*    __restrict__ W_ih,     // [2, 128, 128] (layer 1 used)
    const float*    __restrict__ W_hh,     // [2, 128, 128]
    const float*    __restrict__ bias,     // [2, 128] (layer 1 used)
    const float*    __restrict__ cls_w,    // [128]
    const float*    __restrict__ cls_b,    // [1]
    float*          __restrict__ out)      // [B]
{
    const int b    = blockIdx.x;
    const int tid  = threadIdx.x;
    const int wave = tid >> 6;
    const int lane = tid & 63;
    const int jg   = wave * 16 + (lane >> 2);   // [0,64): owns j = 2jg, 2jg+1
    const int q    = lane & 3;                  // k-quarter [32q, 32q+32)
    const int jm   = lane & 1;                  // task column select
    const int isl1 = (lane >> 1) & 1;           // task layer select
    const int jt   = 2 * jg + jm;               // this lane's task column

    __shared__ int xids[SEQ];                        // 8 KB
    __shared__ __align__(16) _Float16 h0h[2][HID];
    __shared__ __align__(16) _Float16 h1h[2][HID];
    __shared__ __align__(16) float    red[HID];

    const int len   = lengths[b];
    const int lenm1 = len - 1;
    const float LOG2E2 = 2.88539008177793f;          // 2*log2(e)

    for (int i = tid; i < SEQ; i += NTHR) xids[i] = x[b * SEQ + i];
    if (tid < HID) {
        h0h[0][tid] = (_Float16)0.f; h0h[1][tid] = (_Float16)0.f;
        h1h[0][tid] = (_Float16)0.f; h1h[1][tid] = (_Float16)0.f;
    }

    // weights -> VGPRs: pack along k as v2h; [jm][i] for this thread's slice
    v2h whh0[2][16], wih1[2][16], whh1[2][16];
#pragma unroll
    for (int i = 0; i < 16; ++i) {
        const int k = 32 * q + 2 * i;
#pragma unroll
        for (int m = 0; m < 2; ++m) {
            const int j = 2 * jg + m;
            whh0[m][i] = v2h{(_Float16)W_hh[k * HID + j],
                             (_Float16)W_hh[(k + 1) * HID + j]};
            wih1[m][i] = v2h{(_Float16)W_ih[HID * HID + k * HID + j],
                             (_Float16)W_ih[HID * HID + (k + 1) * HID + j]};
            whh1[m][i] = v2h{(_Float16)W_hh[HID * HID + k * HID + j],
                             (_Float16)W_hh[HID * HID + (k + 1) * HID + j]};
        }
    }
    const float b1K = bias[HID + jt] * LOG2E2;       // layer-1 bias (task col)

    __syncthreads();                                 // one-time: xids + zeroed h

    // Y-gather ring (depth 2) for this lane's task column
    _Float16 zA = Y[(size_t)xids[0] * HID + jt];
    _Float16 zB = Y[(size_t)xids[min(1, lenm1)] * HID + jt];

    int ph = 0, pf = 0;

    // tanh(z) with pre-scaled arg zK = z*2*log2(e): 1 - 2/(exp2(zK)+1)
#define TANH_PRE(ZK) (1.0f - 2.0f * fast_rcp(__builtin_amdgcn_exp2f(ZK) + 1.0f))

#define DO_PHASE(RD, WR, ZREG)                                              \
    {                                                                       \
        const uint4* h0p = (const uint4*)&h0h[RD][0] + q * 4;               \
        const uint4* h1p = (const uint4*)&h1h[RD][0] + q * 4;               \
        const float zcK = (float)ZREG * LOG2E2;                             \
        {                                                                   \
            const int tn = xids[min(ph + 2, lenm1)];                        \
            ZREG = Y[(size_t)tn * HID + jt];                                \
        }                                                                   \
        float a0_0 = 0.f, a0_1 = 0.f;   /* Whh0 . h0 for j0, j1 */          \
        float aA_0 = 0.f, aA_1 = 0.f;   /* Wih1 . h0 */                     \
        float aB_0 = 0.f, aB_1 = 0.f;   /* Whh1 . h1 */                     \
        _Pragma("unroll")                                                   \
        for (int c = 0; c < 4; ++c) {                                       \
            const uint4 hu = h0p[c];                                        \
            const uint4 gu = h1p[c];                                        \
            a0_0 = dot2(BCH(hu.x), whh0[0][4*c+0], a0_0);                   \
            a0_0 = dot2(BCH(hu.y), whh0[0][4*c+1], a0_0);                   \
            a0_0 = dot2(BCH(hu.z), whh0[0][4*c+2], a0_0);                   \
            a0_0 = dot2(BCH(hu.w), whh0[0][4*c+3], a0_0);                   \
            a0_1 = dot2(BCH(hu.x), whh0[1][4*c+0], a0_1);                   \
            a0_1 = dot2(BCH(hu.y), whh0[1][4*c+1], a0_1);                   \
            a0_1 = dot2(BCH(hu.z), whh0[1][4*c+2], a0_1);                   \
            a0_1 = dot2(BCH(hu.w), whh0[1][4*c+3], a0_1);                   \
            aA_0 = dot2(BCH(hu.x), wih1[0][4*c+0], aA_0);                   \
            aA_0 = dot2(BCH(hu.y), wih1[0][4*c+1], aA_0);                   \
            aA_0 = dot2(BCH(hu.z), wih1[0][4*c+2], aA_0);                   \
            aA_0 = dot2(BCH(hu.w), wih1[0][4*c+3], aA_0);                   \
            aA_1 = dot2(BCH(hu.x), wih1[1][4*c+0], aA_1);                   \
            aA_1 = dot2(BCH(hu.y), wih1[1][4*c+1], aA_1);                   \
            aA_1 = dot2(BCH(hu.z), wih1[1][4*c+2], aA_1);                   \
            aA_1 = dot2(BCH(hu.w), wih1[1][4*c+3], aA_1);                   \
            aB_0 = dot2(BCH(gu.x), whh1[0][4*c+0], aB_0);                   \
            aB_0 = dot2(BCH(gu.y), whh1[0][4*c+1], aB_0);                   \
            aB_0 = dot2(BCH(gu.z), whh1[0][4*c+2], aB_0);                   \
            aB_0 = dot2(BCH(gu.w), whh1[0][4*c+3], aB_0);                   \
            aB_1 = dot2(BCH(gu.x), whh1[1][4*c+0], aB_1);                   \
            aB_1 = dot2(BCH(gu.y), whh1[1][4*c+1], aB_1);                   \
            aB_1 = dot2(BCH(gu.z), whh1[1][4*c+2], aB_1);                   \
            aB_1 = dot2(BCH(gu.w), whh1[1][4*c+3], aB_1);                   \
        }                                                                   \
        float s0_0 = quad_reduce(a0_0);                                     \
        float s0_1 = quad_reduce(a0_1);                                     \
        float s1_0 = quad_reduce(aA_0 + aB_0);                              \
        float s1_1 = quad_reduce(aA_1 + aB_1);                              \
        const float sj  = jm  ? (isl1 ? s1_1 : s0_1) : (isl1 ? s1_0 : s0_0);\
        const float cj  = isl1 ? b1K : zcK;                                 \
        const float t   = TANH_PRE(__builtin_fmaf(sj, LOG2E2, cj));         \
        if (!isl1) { if (ph < len) h0h[WR][jt] = (_Float16)t; }             \
        else       { if (ph >= 1)  h1h[WR][jt] = (_Float16)t; }             \
        barrier_lds();                                                      \
    }

    for (;;) {
        DO_PHASE(0, 1, zA)
        ++ph;
        if (ph > len) { pf = 1; break; }
        DO_PHASE(1, 0, zB)
        ++ph;
        if (ph > len) { pf = 0; break; }
    }
#undef DO_PHASE
#undef TANH_PRE

    // classifier: out[b] = sigmoid(h1(len-1) . cls_w + cls_b)
    if (tid < HID) red[tid] = (float)h1h[pf][tid] * cls_w[tid];
    __syncthreads();
    if (tid == 0) {
        float s = 0.f;
        for (int i = 0; i < HID; ++i) s += red[i];
        s += cls_b[0];
        out[b] = fast_rcp(1.0f + __expf(-s));
    }
}

extern "C" void kernel_launch(void* const* d_in, const int* in_sizes, int n_in,
                              void* d_out, int out_size, void* d_ws, size_t ws_size,
                              hipStream_t stream) {
    const int*   x       = (const int*)  d_in[0];
    const int*   lengths = (const int*)  d_in[1];
    const float* emb     = (const float*)d_in[2];
    const float* W_ih    = (const float*)d_in[3];
    const float* W_hh    = (const float*)d_in[4];
    const float* bias    = (const float*)d_in[5];
    const float* cls_w   = (const float*)d_in[6];
    const float* cls_b   = (const float*)d_in[7];
    float*       out     = (float*)      d_out;

    _Float16* Yws = (_Float16*)d_ws;     // 50000*128*2 B = 12.8 MB

    emb_proj_kernel<<<2048, 512, 0, stream>>>(emb, W_ih, bias, Yws);
    rnn_dot2_kernel<<<BATCH, NTHR, 0, stream>>>(
        x, lengths, Yws, W_ih, W_hh, bias, cls_w, cls_b, out);
}